// Round 6
// baseline (120.419 us; speedup 1.0000x reference)
//
#include <hip/hip_runtime.h>

#define NV 30000
#define NB 128
#define NS 512
#define ND 300
#define NC 300
#define CP 304
#define KP 320
#define MASK_NEG -1e9f
#define SQ_EPS 1e-8f

typedef __attribute__((ext_vector_type(4))) float f32x4;
typedef __attribute__((ext_vector_type(8))) __bf16 bf16x8;

__device__ __forceinline__ unsigned int f2bfu(float x){
  unsigned int u = __float_as_uint(x);
  u += 0x7FFFu + ((u >> 16) & 1u);
  return u >> 16;
}
__device__ __forceinline__ unsigned short f2bf(float x){ return (unsigned short)f2bfu(x); }

// pre-swizzle: XOR the 16B-chunk index (bits 3..5 of k) with (row&7)
__device__ __forceinline__ int swzk(int row, int k){
  return (k & ~0x38) | (((((k >> 3) & 7) ^ (row & 7)) & 7) << 3);
}

__device__ __forceinline__ float bsum512(float v, float* red, int tid){
  red[tid] = v; __syncthreads();
  float s = 0.f;
  if (tid < 64){
    s = red[tid]+red[tid+64]+red[tid+128]+red[tid+192]
      + red[tid+256]+red[tid+320]+red[tid+384]+red[tid+448];
    #pragma unroll
    for (int off = 32; off > 0; off >>= 1) s += __shfl_xor(s, off);
    if (tid == 0) red[0] = s;
  }
  __syncthreads();
  s = red[0];
  __syncthreads();
  return s;
}

__device__ __forceinline__ float bmax512(float v, float* red, int tid){
  red[tid] = v; __syncthreads();
  float s = MASK_NEG;
  if (tid < 64){
    s = red[tid];
    #pragma unroll
    for (int o = 64; o < 512; o += 64) s = fmaxf(s, red[tid+o]);
    #pragma unroll
    for (int off = 32; off > 0; off >>= 1) s = fmaxf(s, __shfl_xor(s, off));
    if (tid == 0) red[0] = s;
  }
  __syncthreads();
  s = red[0];
  __syncthreads();
  return s;
}

// ---------------- KPREP ----------------
// blocks 0..24: Ws transpose -> WTC rows 0..319 (bf16, pre-swizzled)
// block 25: zero WTC rows 452..511; bs2 -> BC[131]
// block 26: WTC row 451 = Ws @ bs
// blocks 27..154: aspect b -> BC[b] (bs.t_b), WTC row 320+b = Ws @ (Watt @ cap_b)
// blocks 155..157: guide k -> BC[128+k], WTC row 448+k = Ws @ (Gw @ gtil_k)
__global__ __launch_bounds__(512) void kprep(
    const float* __restrict__ Ws, const float* __restrict__ Watt,
    const float* __restrict__ Gw, const float* __restrict__ bs,
    const float* __restrict__ gcap, const int* __restrict__ aspect,
    const float* __restrict__ embed, const float* __restrict__ Wa,
    const float* __restrict__ ba,
    unsigned short* __restrict__ WTC, float* __restrict__ BC)
{
  int bid = blockIdx.x, tid = threadIdx.x;
  int lane = tid & 63, w = tid >> 6;
  __shared__ float sh[64*65];
  float* vecL = sh;          // [320]
  float* capL = sh + 320;    // [320]
  float* tL   = sh + 640;    // [320]
  float* red  = sh + 960;    // [512]

  if (bid < 25) {
    float (*t)[65] = (float(*)[65])sh;
    int kt = bid / 5, nt = bid - kt*5;
    #pragma unroll
    for (int i = 0; i < 8; i++){
      int idx = i*512 + tid;
      int r = idx >> 6, c = idx & 63;
      int gk = kt*64 + r, gn = nt*64 + c;
      t[r][c] = (gk < ND && gn < NC) ? Ws[gk*NC + gn] : 0.f;
    }
    __syncthreads();
    #pragma unroll
    for (int i = 0; i < 8; i++){
      int idx = i*512 + tid;
      int n = idx >> 6, k = idx & 63;
      int row = nt*64 + n, gk = kt*64 + k;
      WTC[row*KP + swzk(row, gk)] = f2bf(t[k][n]);
    }
  } else if (bid == 25) {
    for (int i = tid; i < 60*KP; i += 512) WTC[452*KP + i] = 0;
    float bv = (tid < NC) ? bs[tid] : 0.f;
    float s2 = bsum512(bv*bv, red, tid);
    if (tid == 0) BC[131] = s2;
  } else if (bid == 26) {
    if (tid < 320) vecL[tid] = (tid < NC) ? bs[tid] : 0.f;
    __syncthreads();
    for (int d = w; d < 320; d += 8){
      float acc = 0.f;
      if (d < ND){
        const float* wr = Ws + (size_t)d*NC;
        #pragma unroll
        for (int j = 0; j < 5; j++){
          int c = j*64 + lane;
          float wv = (c < NC) ? wr[c] : 0.f;
          acc += wv*vecL[c];
        }
        #pragma unroll
        for (int off = 32; off > 0; off >>= 1) acc += __shfl_xor(acc, off);
      }
      if (lane == 0) WTC[451*KP + swzk(451, d)] = (d < ND) ? f2bf(acc) : (unsigned short)0;
    }
  } else if (bid < 155) {
    int b = bid - 27;
    int a = aspect[b];
    if (tid < 320) vecL[tid] = (tid < ND) ? embed[(size_t)a*ND + tid] : 0.f;
    __syncthreads();
    float z = 0.f;
    if (tid < NC){
      float p0=0.f,p1=0.f,p2=0.f,p3=0.f,p4=0.f,p5=0.f;
      for (int d = 0; d < 300; d += 6){
        p0 += Wa[(d+0)*NC + tid]*vecL[d+0];
        p1 += Wa[(d+1)*NC + tid]*vecL[d+1];
        p2 += Wa[(d+2)*NC + tid]*vecL[d+2];
        p3 += Wa[(d+3)*NC + tid]*vecL[d+3];
        p4 += Wa[(d+4)*NC + tid]*vecL[d+4];
        p5 += Wa[(d+5)*NC + tid]*vecL[d+5];
      }
      z = ba[tid] + ((p0+p1)+(p2+p3)+(p4+p5));
    }
    float sq = bsum512((tid < NC) ? z*z : 0.f, red, tid);
    float ssv = (sq/(1.f+sq))/sqrtf(sq + SQ_EPS);
    if (tid < 320) capL[tid] = (tid < NC) ? z*ssv : 0.f;
    __syncthreads();
    // pass1: tL[c] = Watt[c,:].cap
    for (int c = w; c < NC; c += 8){
      const float* wr = Watt + (size_t)c*NC;
      float acc = 0.f;
      #pragma unroll
      for (int j = 0; j < 5; j++){
        int d = j*64 + lane;
        float wv = (d < ND) ? wr[d] : 0.f;
        acc += wv*capL[d];
      }
      #pragma unroll
      for (int off = 32; off > 0; off >>= 1) acc += __shfl_xor(acc, off);
      if (lane == 0) tL[c] = acc;
    }
    __syncthreads();
    if (tid < 20) tL[300 + tid] = 0.f;
    float bst = bsum512((tid < NC) ? bs[tid]*tL[tid] : 0.f, red, tid);
    if (tid == 0) BC[b] = bst;
    // pass2: WTC row 320+b : w2[d] = Ws[d,:].tL
    int row = 320 + b;
    for (int d = w; d < 320; d += 8){
      float acc = 0.f;
      if (d < ND){
        const float* wr = Ws + (size_t)d*NC;
        #pragma unroll
        for (int j = 0; j < 5; j++){
          int c = j*64 + lane;
          float wv = (c < NC) ? wr[c] : 0.f;
          acc += wv*tL[c];
        }
        #pragma unroll
        for (int off = 32; off > 0; off >>= 1) acc += __shfl_xor(acc, off);
      }
      if (lane == 0) WTC[row*KP + swzk(row, d)] = (d < ND) ? f2bf(acc) : (unsigned short)0;
    }
  } else {
    int k = bid - 155;
    if (tid < 320) vecL[tid] = (tid < NC) ? gcap[k*NC + tid] : 0.f;
    __syncthreads();
    float g = (tid < 320) ? vecL[tid] : 0.f;
    float sq = bsum512((tid < NC) ? g*g : 0.f, red, tid);
    float ssv = (sq/(1.f+sq))/sqrtf(sq + SQ_EPS);
    if (tid < 320) capL[tid] = g*ssv;
    __syncthreads();
    for (int c = w; c < NC; c += 8){
      const float* wr = Gw + (size_t)c*NC;
      float acc = 0.f;
      #pragma unroll
      for (int j = 0; j < 5; j++){
        int d = j*64 + lane;
        float wv = (d < ND) ? wr[d] : 0.f;
        acc += wv*capL[d];
      }
      #pragma unroll
      for (int off = 32; off > 0; off >>= 1) acc += __shfl_xor(acc, off);
      if (lane == 0) tL[c] = acc;
    }
    __syncthreads();
    if (tid < 20) tL[300 + tid] = 0.f;
    float bsg = bsum512((tid < NC) ? bs[tid]*tL[tid] : 0.f, red, tid);
    if (tid == 0) BC[128 + k] = bsg;
    int row = 448 + k;
    for (int d = w; d < 320; d += 8){
      float acc = 0.f;
      if (d < ND){
        const float* wr = Ws + (size_t)d*NC;
        #pragma unroll
        for (int j = 0; j < 5; j++){
          int c = j*64 + lane;
          float wv = (c < NC) ? wr[c] : 0.f;
          acc += wv*tL[c];
        }
        #pragma unroll
        for (int off = 32; off > 0; off >>= 1) acc += __shfl_xor(acc, off);
      }
      if (lane == 0) WTC[row*KP + swzk(row, d)] = (d < ND) ? f2bf(acc) : (unsigned short)0;
    }
  }
}

// ---------------- K1F: one GEMM embed[30000x320] @ WTC[512x320]^T ----------------
// cols 0..319 -> e.e only; 320..447 -> EtT; 448..451 -> ETS {g0,g1,g2,ebs}
#define LDK 72
__global__ __launch_bounds__(512, 4) void k1f(
    const float* __restrict__ embed, const unsigned short* __restrict__ WTC,
    float* __restrict__ EtT, float* __restrict__ ETS)
{
  __shared__ unsigned short lds_a[64*LDK];
  __shared__ unsigned short lds_b[512*64];   // pre-swizzled
  __shared__ float e2part[3][64];
  int tid = threadIdx.x, lane = tid & 63, wid = tid >> 6;
  int wrow = wid >> 2, wcol = wid & 3;
  int rowbase = blockIdx.x * 64;
  f32x4 acc[2][8];
  f32x4 zero = {0.f,0.f,0.f,0.f};
  #pragma unroll
  for (int m = 0; m < 2; m++)
    #pragma unroll
    for (int n = 0; n < 8; n++) acc[m][n] = zero;

  float4 pa[2];
  auto loadA = [&](int k0){
    #pragma unroll
    for (int r = 0; r < 2; r++){
      int id = r*512 + tid;
      int row = id >> 4, k4 = (id & 15) << 2;
      int grow = rowbase + row, gk = k0 + k4;
      float4 v = {0.f,0.f,0.f,0.f};
      if (grow < NV && gk < ND) v = *(const float4*)(embed + (size_t)grow*ND + gk);
      pa[r] = v;
    }
  };
  auto writeA = [&](){
    #pragma unroll
    for (int r = 0; r < 2; r++){
      int id = r*512 + tid;
      int row = id >> 4, k4 = (id & 15) << 2;
      uint2 pk;
      pk.x = f2bfu(pa[r].x) | (f2bfu(pa[r].y) << 16);
      pk.y = f2bfu(pa[r].z) | (f2bfu(pa[r].w) << 16);
      *(uint2*)(lds_a + row*LDK + k4) = pk;
    }
  };
  auto stageB = [&](int k0){
    uint4 pb[8];
    #pragma unroll
    for (int r = 0; r < 8; r++){
      int id = r*512 + tid;
      pb[r] = *(const uint4*)(WTC + (size_t)(id >> 3)*KP + k0 + (id & 7)*8);
    }
    #pragma unroll
    for (int r = 0; r < 8; r++){
      int id = r*512 + tid;
      *(uint4*)((char*)lds_b + id*16) = pb[r];
    }
  };

  loadA(0);
  writeA();
  stageB(0);
  loadA(64);
  __syncthreads();
  for (int step = 0; step < 5; step++){
    #pragma unroll
    for (int kk = 0; kk < 64; kk += 32){
      int kidx = kk + (lane >> 4)*8;
      bf16x8 af[2];
      #pragma unroll
      for (int m = 0; m < 2; m++)
        af[m] = *(const bf16x8*)(lds_a + (wrow*32 + (lane & 15) + m*16)*LDK + kidx);
      #pragma unroll
      for (int n = 0; n < 8; n++){
        int jrow = wcol*128 + n*16 + (lane & 15);
        int ch = ((kidx >> 3) & 7) ^ (jrow & 7);
        bf16x8 bv = *(const bf16x8*)((const char*)lds_b + jrow*128 + ch*16);
        #pragma unroll
        for (int m = 0; m < 2; m++)
          acc[m][n] = __builtin_amdgcn_mfma_f32_16x16x32_bf16(af[m], bv, acc[m][n], 0, 0, 0);
      }
    }
    __syncthreads();
    if (step < 4){
      writeA();
      stageB((step+1)*64);
      if (step < 3) loadA((step+2)*64);
      __syncthreads();
    }
  }

  // stores
  int rloc = wrow*32 + ((lane >> 4) << 2);
  #pragma unroll
  for (int m = 0; m < 2; m++)
    #pragma unroll
    for (int n = 0; n < 8; n++){
      int col = wcol*128 + n*16 + (lane & 15);
      #pragma unroll
      for (int j = 0; j < 4; j++){
        int grow = rowbase + rloc + m*16 + j;
        if (grow < NV){
          if (col >= 320 && col < 448)      EtT[(size_t)grow*128 + (col - 320)] = acc[m][n][j];
          else if (col >= 448 && col < 452) ETS[(size_t)grow*8 + (col - 448)] = acc[m][n][j];
        }
      }
    }
  // e.e
  #pragma unroll
  for (int m = 0; m < 2; m++)
    #pragma unroll
    for (int j = 0; j < 4; j++){
      float p = 0.f;
      #pragma unroll
      for (int n = 0; n < 8; n++)
        if (wcol*128 + n*16 < 320){ float t = acc[m][n][j]; p += t*t; }
      #pragma unroll
      for (int off = 1; off < 16; off <<= 1) p += __shfl_xor(p, off);
      if ((lane & 15) == 0 && wcol < 3) e2part[wcol][rloc + m*16 + j] = p;
    }
  __syncthreads();
  if (tid < 64){
    int grow = rowbase + tid;
    if (grow < NV)
      ETS[(size_t)grow*8 + 4] = e2part[0][tid] + e2part[1][tid] + e2part[2][tid];
  }
}

// ---------------- K45A: stats+softmax (all 512), gather own 256 tokens ----------------
__global__ __launch_bounds__(512) void k45a(
    const int* __restrict__ sentence, const float* __restrict__ alpha,
    const float* __restrict__ scale_p, const float* __restrict__ embed,
    const float* __restrict__ EtT, const float* __restrict__ ETS,
    const float* __restrict__ BC, float* __restrict__ SBB, float* __restrict__ PRT)
{
  int bid = blockIdx.x;
  int b = bid >> 1, hb = bid & 1;
  int tid = threadIdx.x, lane = tid & 63, w = tid >> 6;
  __shared__ float red[512];
  __shared__ float cfs[NS*3];
  __shared__ int toksh[NS];
  __shared__ float cap8[8][3][CP];

  int idx = (b << 9) + tid;
  int tok = sentence[idx];
  float al = alpha[idx];
  toksh[tid] = tok;
  float et = EtT[(size_t)tok*128 + b];
  float4 eg = *(const float4*)(ETS + (size_t)tok*8);   // g0,g1,g2,ebs
  float e2 = ETS[(size_t)tok*8 + 4];
  float bst = BC[b];
  float bsg0 = BC[128], bsg1 = BC[129], bsg2 = BC[130], bs2 = BC[131];

  float sq = al*al*e2 + 2.f*al*eg.w + bs2;
  float ssv = (sq/(1.f+sq))/sqrtf(sq + SQ_EPS);
  float scv = (tok != 0) ? ssv*(al*et + bst) : MASK_NEG;
  float u0 = ssv*(al*eg.x + bsg0);
  float u1 = ssv*(al*eg.y + bsg1);
  float u2 = ssv*(al*eg.z + bsg2);

  float m = bmax512(scv, red, tid);
  float e = expf(scv - m);
  float Z = bsum512(e, red, tid);
  float nw = e / Z;
  float mk = fmaxf(u0, fmaxf(u1, u2));
  float e0 = expf(u0-mk), e1 = expf(u1-mk), e2k = expf(u2-mk);
  float wf = nw * scale_p[0] / (e0+e1+e2k);
  float w0 = e0*wf, w1 = e1*wf, w2 = e2k*wf;
  float ca = ssv * al;
  cfs[tid*3+0] = w0*ca; cfs[tid*3+1] = w1*ca; cfs[tid*3+2] = w2*ca;
  float sb0 = bsum512(w0*ssv, red, tid);
  float sb1 = bsum512(w1*ssv, red, tid);
  float sb2 = bsum512(w2*ssv, red, tid);
  if (hb == 0 && tid == 0){ SBB[b*3+0] = sb0; SBB[b*3+1] = sb1; SBB[b*3+2] = sb2; }
  __syncthreads();

  // gather this half's 256 tokens: wave w handles 32
  f32x4 A0 = {0.f,0.f,0.f,0.f}, A1 = A0, A2 = A0, R0 = A0, R1 = A0, R2 = A0;
  int c0 = lane << 2;
  int c1 = 256 + (lane << 2);
  bool rem = lane < 11;
  int base = (hb << 8) + (w << 5);
  #pragma unroll 4
  for (int i = 0; i < 32; i++){
    int s = base + i;
    int t = toksh[s];
    const float* er = embed + (size_t)t*ND;
    float4 y = *(const float4*)(er + c0);
    float cf0 = cfs[s*3+0], cf1 = cfs[s*3+1], cf2 = cfs[s*3+2];
    f32x4 yv = {y.x, y.y, y.z, y.w};
    A0 += cf0*yv; A1 += cf1*yv; A2 += cf2*yv;
    if (rem){
      float4 y2 = *(const float4*)(er + c1);
      f32x4 y2v = {y2.x, y2.y, y2.z, y2.w};
      R0 += cf0*y2v; R1 += cf1*y2v; R2 += cf2*y2v;
    }
  }
  *(f32x4*)&cap8[w][0][c0] = A0;
  *(f32x4*)&cap8[w][1][c0] = A1;
  *(f32x4*)&cap8[w][2][c0] = A2;
  if (rem){
    *(f32x4*)&cap8[w][0][c1] = R0;
    *(f32x4*)&cap8[w][1][c1] = R1;
    *(f32x4*)&cap8[w][2][c1] = R2;
  }
  __syncthreads();
  for (int p = tid; p < 3*CP; p += 512){
    int k = p / CP, c = p - k*CP;
    float v = 0.f;
    if (c < 300){
      #pragma unroll
      for (int w8 = 0; w8 < 8; w8++) v += cap8[w8][k][c];
    }
    PRT[((size_t)bid*3 + k)*CP + c] = v;
  }
}

// ---------------- K45B: Q@Ws + sb*bs -> squash norms -> out ----------------
__global__ __launch_bounds__(512) void k45b(
    const float* __restrict__ PRT, const float* __restrict__ SBB,
    const float* __restrict__ bs, const float* __restrict__ Ws,
    float* __restrict__ out)
{
  int b = blockIdx.x, tid = threadIdx.x;
  __shared__ float Qs[3][CP];
  __shared__ float red[512];
  for (int p = tid; p < 3*CP; p += 512){
    int k = p / CP, c = p - k*CP;
    float v = 0.f;
    if (c < 300)
      v = PRT[((size_t)(2*b)*3 + k)*CP + c] + PRT[((size_t)(2*b+1)*3 + k)*CP + c];
    Qs[k][c] = v;
  }
  __syncthreads();
  float v0 = 0.f, v1 = 0.f, v2 = 0.f;
  if (tid < NC){
    float a0=0.f,a1=0.f,a2=0.f,b0=0.f,b1=0.f,b2=0.f;
    for (int d = 0; d < 300; d += 2){
      float wA = Ws[d*NC + tid], wB = Ws[(d+1)*NC + tid];
      a0 += wA*Qs[0][d]; b0 += wB*Qs[0][d+1];
      a1 += wA*Qs[1][d]; b1 += wB*Qs[1][d+1];
      a2 += wA*Qs[2][d]; b2 += wB*Qs[2][d+1];
    }
    float bc = bs[tid];
    v0 = a0+b0 + SBB[b*3+0]*bc;
    v1 = a1+b1 + SBB[b*3+1]*bc;
    v2 = a2+b2 + SBB[b*3+2]*bc;
  }
  float s0 = bsum512(v0*v0, red, tid);
  float s1 = bsum512(v1*v1, red, tid);
  float s2 = bsum512(v2*v2, red, tid);
  if (tid == 0){
    out[b*3+0] = (s0/(1.f+s0))*sqrtf(s0)/sqrtf(s0 + SQ_EPS);
    out[b*3+1] = (s1/(1.f+s1))*sqrtf(s1)/sqrtf(s1 + SQ_EPS);
    out[b*3+2] = (s2/(1.f+s2))*sqrtf(s2)/sqrtf(s2 + SQ_EPS);
  }
}

extern "C" void kernel_launch(void* const* d_in, const int* in_sizes, int n_in,
                              void* d_out, int out_size, void* d_ws, size_t ws_size,
                              hipStream_t stream)
{
  (void)in_sizes; (void)n_in; (void)out_size; (void)ws_size;
  const int*   sentence = (const int*)d_in[0];
  const int*   aspect   = (const int*)d_in[1];
  const float* alpha    = (const float*)d_in[2];
  const float* embed    = (const float*)d_in[3];
  const float* Ws       = (const float*)d_in[4];
  const float* bs       = (const float*)d_in[5];
  const float* Wa       = (const float*)d_in[6];
  const float* ba       = (const float*)d_in[7];
  const float* Watt     = (const float*)d_in[8];
  const float* gcap     = (const float*)d_in[9];
  const float* gw       = (const float*)d_in[10];
  const float* scale    = (const float*)d_in[11];
  float* out = (float*)d_out;

  char* w = (char*)d_ws;
  auto alloc = [&](size_t bytes)->char*{
    char* p = w; w += (bytes + 255) & ~(size_t)255; return p;
  };
  unsigned short* WTC = (unsigned short*)alloc((size_t)512*KP*2);
  float* ETT = (float*)alloc((size_t)NV*128*4);
  float* ETS = (float*)alloc((size_t)NV*8*4);
  float* BC  = (float*)alloc(132*4);
  float* SBB = (float*)alloc(NB*3*4);
  float* PRT = (float*)alloc((size_t)256*3*CP*4);

  kprep<<<158, 512, 0, stream>>>(Ws, Watt, gw, bs, gcap, aspect, embed, Wa, ba, WTC, BC);
  k1f<<<(NV + 63)/64, 512, 0, stream>>>(embed, WTC, ETT, ETS);
  k45a<<<256, 512, 0, stream>>>(sentence, alpha, scale, embed, ETT, ETS, BC, SBB, PRT);
  k45b<<<NB, 512, 0, stream>>>(PRT, SBB, bs, Ws, out);
}